// Round 3
// baseline (112.687 us; speedup 1.0000x reference)
//
#include <hip/hip_runtime.h>
#include <hip/hip_bf16.h>

#define HID 1024
#define MROWS 16384
#define BM 64
#define BN 512
#define BK 64
#define NT (HID / BK)  // 16 K-tiles

typedef __bf16 bf16;
typedef __bf16 bf16x8 __attribute__((ext_vector_type(8)));
typedef float f32x4 __attribute__((ext_vector_type(4)));

#define MFMA(va, vb, vc) __builtin_amdgcn_mfma_f32_16x16x32_bf16(va, vb, vc, 0, 0, 0)

// ---------------------------------------------------------------------------
// wt_k: fold 16-point cos matrix into W, transpose, cast to bf16.
// Wt[n][q*64+d] = sum_qp ct[(q*qp)&15] * W[qp*64+d][n]
// Block: 16 n-columns, all k. LDS-transposed, pad 17 to kill bank conflicts.
// ---------------------------------------------------------------------------
__global__ __launch_bounds__(256) void wt_k(const float* __restrict__ W,
                                            bf16* __restrict__ Wt) {
    __shared__ float Wl[1024][17];  // 69632 B
    const int tid = threadIdx.x;
    const int n0 = blockIdx.x * 16;

    // load W[:, n0:n0+16] coalesced: lane = r*4+nq reads float4
    {
        int r = tid >> 2, nq = tid & 3;
#pragma unroll
        for (int p = 0; p < 16; ++p) {
            int k = p * 64 + r;
            float4 v = *(const float4*)&W[(size_t)k * HID + n0 + nq * 4];
            Wl[k][nq * 4 + 0] = v.x; Wl[k][nq * 4 + 1] = v.y;
            Wl[k][nq * 4 + 2] = v.z; Wl[k][nq * 4 + 3] = v.w;
        }
    }
    __syncthreads();

    const float ct[16] = {
        1.0f,  0.92387953f,  0.70710678f,  0.38268343f,
        0.0f, -0.38268343f, -0.70710678f, -0.92387953f,
       -1.0f, -0.92387953f, -0.70710678f, -0.38268343f,
        0.0f,  0.38268343f,  0.70710678f,  0.92387953f};

    const int d = tid & 63, ng = tid >> 6;
#pragma unroll
    for (int nn = 0; nn < 4; ++nn) {
        int n = ng * 4 + nn;
        float wv[16];
#pragma unroll
        for (int qp = 0; qp < 16; ++qp) wv[qp] = Wl[qp * 64 + d][n];
#pragma unroll
        for (int q = 0; q < 16; ++q) {
            float acc = 0.0f;
#pragma unroll
            for (int qp = 0; qp < 16; ++qp) acc += wv[qp] * ct[(q * qp) & 15];
            Wt[(size_t)(n0 + n) * HID + q * 64 + d] = (bf16)acc;  // lanes d: coalesced 128B
        }
    }
}

// ---------------------------------------------------------------------------
// Fused LN+sin+GEMM.  C[m][n] = sum_k (0.5 sin(2 LN(x)))[m][k] * Wt[n][k] + bias[n]
// Block: BM=64 exclusive M-panel x BN=512. 8 waves partition N (64 each).
// A: computed in-block, reg-staged into 16 KiB swizzled dbuf LDS.
// B: direct global bf16x8 fragment loads (Wt is L2-resident), reg dbuf.
// One lgkmcnt(0)+s_barrier per K-tile; vmem waits compiler-managed.
// ---------------------------------------------------------------------------
__global__ __launch_bounds__(512, 2) void gemm_k(const float* __restrict__ x,
                                                 const float* __restrict__ gamma,
                                                 const float* __restrict__ beta,
                                                 const bf16* __restrict__ Bt,
                                                 const float* __restrict__ bias,
                                                 float* __restrict__ C) {
    __shared__ __attribute__((aligned(16))) char sA[2][BM * BK * 2];  // 2 x 8 KiB
    __shared__ float sG[HID];
    __shared__ float sBt[HID];

    const int tid = threadIdx.x;
    const int w = tid >> 6, ln = tid & 63;
    const int fr = ln & 15, fq = ln >> 4;
    const int bm = blockIdx.x & 255;   // bn is slow index: round 1 = bn0 (cold stats)
    const int bn = blockIdx.x >> 8;
    const int m0 = bm * BM;
    const int n0 = bn * BN + w * 64;

    // gamma/beta -> LDS (read per K-tile with broadcast-friendly pattern)
    *(float2*)&sG[tid * 2] = *(const float2*)&gamma[tid * 2];
    *(float2*)&sBt[tid * 2] = *(const float2*)&beta[tid * 2];
    asm volatile("s_waitcnt lgkmcnt(0)" ::: "memory");
    __builtin_amdgcn_s_barrier();

    // ---- stats: row = tid>>3, 8 lanes per row, shuffle-only reduce
    const int row = tid >> 3, g = tid & 7;
    const float* xr = x + (size_t)(m0 + row) * HID;
    float s = 0.f, ss = 0.f;
#pragma unroll 8
    for (int i = 0; i < 32; ++i) {
        float4 v = *(const float4*)&xr[i * 32 + g * 4];
        s += v.x + v.y + v.z + v.w;
        ss += v.x * v.x + v.y * v.y + v.z * v.z + v.w * v.w;
    }
#pragma unroll
    for (int off = 4; off; off >>= 1) {
        s += __shfl_xor(s, off);
        ss += __shfl_xor(ss, off);
    }
    const float mean = s * (1.0f / HID);
    const float rstd = rsqrtf(ss * (1.0f / HID) - mean * mean + 1e-6f);

    const int woff = (row << 7) + ((g ^ (row & 7)) << 4);  // swizzled A write slot

    // LN + 0.5*sin(2h) -> bf16x8, write into sA[buf]
    auto ln_write = [&](int buf, int kt, float4 v0, float4 v1) {
        int c0 = kt * BK + g * 8;
        float4 g0 = *(const float4*)&sG[c0], g1 = *(const float4*)&sG[c0 + 4];
        float4 b0 = *(const float4*)&sBt[c0], b1 = *(const float4*)&sBt[c0 + 4];
        float h[8];
        h[0] = (v0.x - mean) * rstd * g0.x + b0.x;
        h[1] = (v0.y - mean) * rstd * g0.y + b0.y;
        h[2] = (v0.z - mean) * rstd * g0.z + b0.z;
        h[3] = (v0.w - mean) * rstd * g0.w + b0.w;
        h[4] = (v1.x - mean) * rstd * g1.x + b1.x;
        h[5] = (v1.y - mean) * rstd * g1.y + b1.y;
        h[6] = (v1.z - mean) * rstd * g1.z + b1.z;
        h[7] = (v1.w - mean) * rstd * g1.w + b1.w;
        bf16x8 av;
#pragma unroll
        for (int e = 0; e < 8; ++e) av[e] = (bf16)(0.5f * __sinf(2.0f * h[e]));
        *(bf16x8*)&sA[buf][woff] = av;
    };

    f32x4 acc[4][4];
#pragma unroll
    for (int i = 0; i < 4; ++i)
#pragma unroll
        for (int j = 0; j < 4; ++j) acc[i][j] = (f32x4){0.f, 0.f, 0.f, 0.f};

    bf16x8 Bf[2][4][2];
    float4 xva[2][2];

    // ---- prologue: stage A(0) directly, prefetch x chunk 1, B-frags tile 0
    {
        float4 v0 = *(const float4*)&xr[g * 8];
        float4 v1 = *(const float4*)&xr[g * 8 + 4];
        ln_write(0, 0, v0, v1);
    }
    xva[0][0] = *(const float4*)&xr[BK + g * 8];
    xva[0][1] = *(const float4*)&xr[BK + g * 8 + 4];
#pragma unroll
    for (int j = 0; j < 4; ++j)
#pragma unroll
        for (int ks = 0; ks < 2; ++ks)
            Bf[0][j][ks] = *(const bf16x8*)&Bt[(size_t)(n0 + j * 16 + fr) * HID + ks * 32 + fq * 8];
    asm volatile("s_waitcnt lgkmcnt(0)" ::: "memory");
    __builtin_amdgcn_s_barrier();

    // ---- main loop: one barrier per K-tile
#pragma unroll 2
    for (int t = 0; t < NT; ++t) {
        const int cur = t & 1, nxt = cur ^ 1;

        // prefetch B-frags for tile t+1 (into reg dbuf)
        if (t + 1 < NT) {
#pragma unroll
            for (int j = 0; j < 4; ++j)
#pragma unroll
                for (int ks = 0; ks < 2; ++ks)
                    Bf[nxt][j][ks] = *(const bf16x8*)&Bt[(size_t)(n0 + j * 16 + fr) * HID +
                                                         (t + 1) * BK + ks * 32 + fq * 8];
        }
        // prefetch x chunk t+2
        if (t + 2 <= NT - 1) {
            int c0 = (t + 2) * BK + g * 8;
            xva[nxt][0] = *(const float4*)&xr[c0];
            xva[nxt][1] = *(const float4*)&xr[c0 + 4];
        }

        // A-fragments from LDS (swizzled)
        bf16x8 af[4][2];
#pragma unroll
        for (int i = 0; i < 4; ++i)
#pragma unroll
            for (int ks = 0; ks < 2; ++ks) {
                int off = ((i * 16 + fr) << 7) + ((((ks << 2) | fq) ^ (fr & 7)) << 4);
                af[i][ks] = *(const bf16x8*)&sA[cur][off];
            }

        // LN+sin for tile t+1 into the other LDS buffer
        if (t + 1 <= NT - 1) ln_write(nxt, t + 1, xva[cur][0], xva[cur][1]);

        // MFMA cluster
        __builtin_amdgcn_s_setprio(1);
#pragma unroll
        for (int i = 0; i < 4; ++i)
#pragma unroll
            for (int j = 0; j < 4; ++j) {
                acc[i][j] = MFMA(af[i][0], Bf[cur][j][0], acc[i][j]);
                acc[i][j] = MFMA(af[i][1], Bf[cur][j][1], acc[i][j]);
            }
        __builtin_amdgcn_s_setprio(0);

        asm volatile("s_waitcnt lgkmcnt(0)" ::: "memory");
        __builtin_amdgcn_s_barrier();
    }

    // ---- epilogue: C/D layout col = lane&15, row = (lane>>4)*4 + reg
#pragma unroll
    for (int j = 0; j < 4; ++j) {
        int col = n0 + j * 16 + fr;
        float bv = bias[col];
#pragma unroll
        for (int i = 0; i < 4; ++i) {
            int r0 = m0 + i * 16 + fq * 4;
#pragma unroll
            for (int jj = 0; jj < 4; ++jj)
                C[(size_t)(r0 + jj) * HID + col] = acc[i][j][jj] + bv;
        }
    }
}

// ---------------------------------------------------------------------------
extern "C" void kernel_launch(void* const* d_in, const int* in_sizes, int n_in,
                              void* d_out, int out_size, void* d_ws, size_t ws_size,
                              hipStream_t stream) {
    const float* x   = (const float*)d_in[0];
    const float* lng = (const float*)d_in[1];
    const float* lnb = (const float*)d_in[2];
    const float* W   = (const float*)d_in[3];
    const float* db  = (const float*)d_in[4];
    float* out = (float*)d_out;

    bf16* Wt = (bf16*)d_ws;  // 2 MiB

    wt_k<<<HID / 16, 256, 0, stream>>>(W, Wt);
    gemm_k<<<(MROWS / BM) * (HID / BN), 512, 0, stream>>>(x, lng, lnb, Wt, db, out);
}

// Round 4
// 89.242 us; speedup vs baseline: 1.2627x; 1.2627x over previous
//
#include <hip/hip_runtime.h>
#include <hip/hip_bf16.h>

#define HID 1024
#define MROWS 16384  // B*S = 4*4096

typedef __bf16 bf16;
typedef __bf16 bf16x8 __attribute__((ext_vector_type(8)));
typedef __bf16 bf16x4 __attribute__((ext_vector_type(4)));
typedef float f32x4 __attribute__((ext_vector_type(4)));

#define MFMA(va, vb, vc) __builtin_amdgcn_mfma_f32_16x16x32_bf16(va, vb, vc, 0, 0, 0)

// ---------------------------------------------------------------------------
// wt_k: fold 16-point cos matrix into W, transpose, cast bf16.
// Wt[n][q*64+d] = sum_qp ct[(q*qp)&15] * W[qp*64+d][n]
// ---------------------------------------------------------------------------
__global__ __launch_bounds__(256) void wt_k(const float* __restrict__ W,
                                            bf16* __restrict__ Wt) {
    __shared__ float Wl[1024][17];
    const int tid = threadIdx.x;
    const int n0 = blockIdx.x * 16;

    {
        int r = tid >> 2, nq = tid & 3;
#pragma unroll
        for (int p = 0; p < 16; ++p) {
            int k = p * 64 + r;
            float4 v = *(const float4*)&W[(size_t)k * HID + n0 + nq * 4];
            Wl[k][nq * 4 + 0] = v.x; Wl[k][nq * 4 + 1] = v.y;
            Wl[k][nq * 4 + 2] = v.z; Wl[k][nq * 4 + 3] = v.w;
        }
    }
    __syncthreads();

    const float ct[16] = {
        1.0f,  0.92387953f,  0.70710678f,  0.38268343f,
        0.0f, -0.38268343f, -0.70710678f, -0.92387953f,
       -1.0f, -0.92387953f, -0.70710678f, -0.38268343f,
        0.0f,  0.38268343f,  0.70710678f,  0.92387953f};

    const int d = tid & 63, ng = tid >> 6;
#pragma unroll
    for (int nn = 0; nn < 4; ++nn) {
        int n = ng * 4 + nn;
        float wv[16];
#pragma unroll
        for (int qp = 0; qp < 16; ++qp) wv[qp] = Wl[qp * 64 + d][n];
#pragma unroll
        for (int q = 0; q < 16; ++q) {
            float acc = 0.0f;
#pragma unroll
            for (int qp = 0; qp < 16; ++qp) acc += wv[qp] * ct[(q * qp) & 15];
            Wt[(size_t)(n0 + n) * HID + q * 64 + d] = (bf16)acc;
        }
    }
}

// ---------------------------------------------------------------------------
// prep_k: LayerNorm + 0.5*sin(2h) -> bf16 A[16384][1024]  (round-2 proven)
// ---------------------------------------------------------------------------
__global__ __launch_bounds__(256) void prep_k(const float* __restrict__ x,
                                              const float* __restrict__ gamma,
                                              const float* __restrict__ beta,
                                              bf16* __restrict__ A) {
    int row = blockIdx.x;
    int t = threadIdx.x;
    const float4* xr = (const float4*)(x + (size_t)row * HID);
    float4 v = xr[t];

    float s  = v.x + v.y + v.z + v.w;
    float ss = v.x * v.x + v.y * v.y + v.z * v.z + v.w * v.w;
#pragma unroll
    for (int off = 32; off; off >>= 1) {
        s  += __shfl_down(s, off);
        ss += __shfl_down(ss, off);
    }
    __shared__ float red[8];
    int wv = t >> 6, ln = t & 63;
    if (ln == 0) { red[wv] = s; red[4 + wv] = ss; }
    __syncthreads();
    float Sm = red[0] + red[1] + red[2] + red[3];
    float Ss = red[4] + red[5] + red[6] + red[7];
    float mean = Sm * (1.0f / HID);
    float var  = Ss * (1.0f / HID) - mean * mean;
    float rstd = rsqrtf(var + 1e-6f);

    float4 g = ((const float4*)gamma)[t];
    float4 b = ((const float4*)beta)[t];

    float h0 = (v.x - mean) * rstd * g.x + b.x;
    float h1 = (v.y - mean) * rstd * g.y + b.y;
    float h2 = (v.z - mean) * rstd * g.z + b.z;
    float h3 = (v.w - mean) * rstd * g.w + b.w;

    bf16x4 o;
    o[0] = (bf16)(0.5f * __sinf(2.0f * h0));
    o[1] = (bf16)(0.5f * __sinf(2.0f * h1));
    o[2] = (bf16)(0.5f * __sinf(2.0f * h2));
    o[3] = (bf16)(0.5f * __sinf(2.0f * h3));
    ((bf16x4*)(A + (size_t)row * HID))[t] = o;
}

// ---------------------------------------------------------------------------
// gemm: C[m][n] = sum_k A[m][k]*Wt[n][k] + bias[n]
// 256x256 tile, BK=128 (8 K-tiles). A staged in LDS (2x64KB, XOR-swizzled via
// pre-swizzled global source, gload_lds width 16). B direct from L2 (Wt is
// 2 MB, L2-resident), reg double-buffered one K-step ahead. 8 waves (2Mx4N),
// wave tile 128x64. ONE vmcnt(0)+barrier per K-tile (~5000 cyc apart; all
// vmem issued >600cyc before the drain). Compiler manages lgkm waits.
// ---------------------------------------------------------------------------
#define BM 256
#define BN 256
#define BK 128
#define NT (HID / BK)  // 8

__global__ __launch_bounds__(512, 2) void gemm_k(const bf16* __restrict__ A,
                                                 const bf16* __restrict__ Bt,
                                                 const float* __restrict__ bias,
                                                 float* __restrict__ C) {
    __shared__ __attribute__((aligned(16))) char sA[2][65536];

    const int tid = threadIdx.x;
    const int w = tid >> 6, ln = tid & 63;
    const int wm = w >> 2, wn = w & 3;      // 2M x 4N waves
    const int fr = ln & 15, fq = ln >> 4;

    // XCD-chunked bijective swizzle (grid=256)
    int orig = blockIdx.x;
    int wg = (orig & 7) * 32 + (orig >> 3);
    const int bm = wg >> 2, bn = wg & 3;
    const int m0 = bm * BM;
    const int n0 = bn * BN + wn * 64;

    // stage chunk c (8 KB = 32 rows) of A-tile kt into buffer buf.
    // LDS dest linear; global source slot pre-swizzled so phys LDS has
    // slot' = slot ^ (row&7)   (16B slots, 16 per 256B row).
    auto stage = [&](int buf, int kt, int c) {
        int lr = (c << 5) + (tid >> 4);          // local row 0..255
        int sp = (tid & 15) ^ (lr & 7);          // source 16B slot
        const char* g = (const char*)A + (size_t)(m0 + lr) * (HID * 2) +
                        kt * (BK * 2) + (sp << 4);
        // wave-uniform dest base; HW adds lane*16
        char* d = sA[buf] + (c << 13) + (w << 10);
        __builtin_amdgcn_global_load_lds(
            (const __attribute__((address_space(1))) void*)g,
            (__attribute__((address_space(3))) void*)d, 16, 0, 0);
    };

    // swizzled A-frag read: frag i (16 rows), K-step ks (32 cols)
    auto readA = [&](int buf, int i, int ks) -> bf16x8 {
        int row = wm * 128 + i * 16 + fr;
        int off = (row << 8) + ((((ks << 2) | fq) ^ (fr & 7)) << 4);
        return *(const bf16x8*)(sA[buf] + off);
    };

    // direct B-frag load from L2: frag j, tile kt, K-step ks
    auto loadB = [&](int kt, int ks, int j) -> bf16x8 {
        return *(const bf16x8*)&Bt[(size_t)(n0 + (j << 4) + fr) * HID +
                                   kt * BK + ks * 32 + (fq << 3)];
    };

    f32x4 acc[8][4];
#pragma unroll
    for (int i = 0; i < 8; ++i)
#pragma unroll
        for (int j = 0; j < 4; ++j) acc[i][j] = (f32x4){0.f, 0.f, 0.f, 0.f};

    // prologue: stage tile 0, preload B(0,0)
#pragma unroll
    for (int c = 0; c < 8; ++c) stage(0, 0, c);
    bf16x8 b[2][4];
#pragma unroll
    for (int j = 0; j < 4; ++j) b[0][j] = loadB(0, 0, j);
    asm volatile("s_waitcnt vmcnt(0)" ::: "memory");
    __builtin_amdgcn_s_barrier();

#pragma unroll 1
    for (int t = 0; t < NT; ++t) {
        const int cur = t & 1, nxt = cur ^ 1;
#pragma unroll
        for (int ks = 0; ks < 4; ++ks) {
            // stage 2 chunks of tile t+1
            if (t + 1 < NT) {
                stage(nxt, t + 1, ks * 2);
                stage(nxt, t + 1, ks * 2 + 1);
            }
            // prefetch B for next K-step (reg dbuf, static parity)
            const int pb = ks & 1, pn = pb ^ 1;
            if (!(t == NT - 1 && ks == 3)) {
                const int tn = (ks == 3) ? t + 1 : t;
                const int ksn = (ks + 1) & 3;
#pragma unroll
                for (int j = 0; j < 4; ++j) b[pn][j] = loadB(tn, ksn, j);
            }
            // A frags for this K-step
            bf16x8 a[8];
#pragma unroll
            for (int i = 0; i < 8; ++i) a[i] = readA(cur, i, ks);

            __builtin_amdgcn_s_setprio(1);
#pragma unroll
            for (int i = 0; i < 8; ++i)
#pragma unroll
                for (int j = 0; j < 4; ++j)
                    acc[i][j] = MFMA(a[i], b[pb][j], acc[i][j]);
            __builtin_amdgcn_s_setprio(0);
        }
        if (t + 1 < NT) {
            asm volatile("s_waitcnt vmcnt(0)" ::: "memory");
            __builtin_amdgcn_s_barrier();
        }
    }

    // epilogue: C/D layout col = lane&15, row = (lane>>4)*4 + reg
#pragma unroll
    for (int j = 0; j < 4; ++j) {
        int col = n0 + (j << 4) + fr;
        float bv = bias[col];
#pragma unroll
        for (int i = 0; i < 8; ++i) {
            int r0 = m0 + wm * 128 + (i << 4) + (fq << 2);
#pragma unroll
            for (int jj = 0; jj < 4; ++jj)
                C[(size_t)(r0 + jj) * HID + col] = acc[i][j][jj] + bv;
        }
    }
}

// ---------------------------------------------------------------------------
extern "C" void kernel_launch(void* const* d_in, const int* in_sizes, int n_in,
                              void* d_out, int out_size, void* d_ws, size_t ws_size,
                              hipStream_t stream) {
    const float* x   = (const float*)d_in[0];
    const float* lng = (const float*)d_in[1];
    const float* lnb = (const float*)d_in[2];
    const float* W   = (const float*)d_in[3];
    const float* db  = (const float*)d_in[4];
    float* out = (float*)d_out;

    bf16* A  = (bf16*)d_ws;                                     // 32 MB
    bf16* Wt = (bf16*)((char*)d_ws + (size_t)MROWS * HID * 2);  // 2 MB

    wt_k<<<HID / 16, 256, 0, stream>>>(W, Wt);
    prep_k<<<MROWS, 256, 0, stream>>>(x, lng, lnb, A);
    gemm_k<<<(MROWS / BM) * (HID / BN), 512, 0, stream>>>(A, Wt, db, out);
}

// Round 5
// 68.925 us; speedup vs baseline: 1.6349x; 1.2948x over previous
//
#include <hip/hip_runtime.h>
#include <hip/hip_bf16.h>

#define HID 1024
#define MROWS 16384  // B*S = 4*4096

typedef __bf16 bf16;
typedef __bf16 bf16x8 __attribute__((ext_vector_type(8)));
typedef __bf16 bf16x4 __attribute__((ext_vector_type(4)));
typedef float f32x4 __attribute__((ext_vector_type(4)));

#define MFMA(va, vb, vc) __builtin_amdgcn_mfma_f32_16x16x32_bf16(va, vb, vc, 0, 0, 0)

// ---------------------------------------------------------------------------
// wt_k: fold 16-point cos matrix into W, transpose, cast bf16. (round-4 LDS ver)
// Wt[n][q*64+d] = sum_qp ct[(q*qp)&15] * W[qp*64+d][n]
// ---------------------------------------------------------------------------
__global__ __launch_bounds__(256) void wt_k(const float* __restrict__ W,
                                            bf16* __restrict__ Wt) {
    __shared__ float Wl[1024][17];
    const int tid = threadIdx.x;
    const int n0 = blockIdx.x * 16;

    {
        int r = tid >> 2, nq = tid & 3;
#pragma unroll
        for (int p = 0; p < 16; ++p) {
            int k = p * 64 + r;
            float4 v = *(const float4*)&W[(size_t)k * HID + n0 + nq * 4];
            Wl[k][nq * 4 + 0] = v.x; Wl[k][nq * 4 + 1] = v.y;
            Wl[k][nq * 4 + 2] = v.z; Wl[k][nq * 4 + 3] = v.w;
        }
    }
    __syncthreads();

    const float ct[16] = {
        1.0f,  0.92387953f,  0.70710678f,  0.38268343f,
        0.0f, -0.38268343f, -0.70710678f, -0.92387953f,
       -1.0f, -0.92387953f, -0.70710678f, -0.38268343f,
        0.0f,  0.38268343f,  0.70710678f,  0.92387953f};

    const int d = tid & 63, ng = tid >> 6;
#pragma unroll
    for (int nn = 0; nn < 4; ++nn) {
        int n = ng * 4 + nn;
        float wv[16];
#pragma unroll
        for (int qp = 0; qp < 16; ++qp) wv[qp] = Wl[qp * 64 + d][n];
#pragma unroll
        for (int q = 0; q < 16; ++q) {
            float acc = 0.0f;
#pragma unroll
            for (int qp = 0; qp < 16; ++qp) acc += wv[qp] * ct[(q * qp) & 15];
            Wt[(size_t)(n0 + n) * HID + q * 64 + d] = (bf16)acc;
        }
    }
}

// ---------------------------------------------------------------------------
// prep_k: LayerNorm + 0.5*sin(2h) -> bf16 A[16384][1024]  (round-2 proven,
// at its 96 MB HBM floor)
// ---------------------------------------------------------------------------
__global__ __launch_bounds__(256) void prep_k(const float* __restrict__ x,
                                              const float* __restrict__ gamma,
                                              const float* __restrict__ beta,
                                              bf16* __restrict__ A) {
    int row = blockIdx.x;
    int t = threadIdx.x;
    const float4* xr = (const float4*)(x + (size_t)row * HID);
    float4 v = xr[t];

    float s  = v.x + v.y + v.z + v.w;
    float ss = v.x * v.x + v.y * v.y + v.z * v.z + v.w * v.w;
#pragma unroll
    for (int off = 32; off; off >>= 1) {
        s  += __shfl_down(s, off);
        ss += __shfl_down(ss, off);
    }
    __shared__ float red[8];
    int wv = t >> 6, ln = t & 63;
    if (ln == 0) { red[wv] = s; red[4 + wv] = ss; }
    __syncthreads();
    float Sm = red[0] + red[1] + red[2] + red[3];
    float Ss = red[4] + red[5] + red[6] + red[7];
    float mean = Sm * (1.0f / HID);
    float var  = Ss * (1.0f / HID) - mean * mean;
    float rstd = rsqrtf(var + 1e-6f);

    float4 g = ((const float4*)gamma)[t];
    float4 b = ((const float4*)beta)[t];

    float h0 = (v.x - mean) * rstd * g.x + b.x;
    float h1 = (v.y - mean) * rstd * g.y + b.y;
    float h2 = (v.z - mean) * rstd * g.z + b.z;
    float h3 = (v.w - mean) * rstd * g.w + b.w;

    bf16x4 o;
    o[0] = (bf16)(0.5f * __sinf(2.0f * h0));
    o[1] = (bf16)(0.5f * __sinf(2.0f * h1));
    o[2] = (bf16)(0.5f * __sinf(2.0f * h2));
    o[3] = (bf16)(0.5f * __sinf(2.0f * h3));
    ((bf16x4*)(A + (size_t)row * HID))[t] = o;
}

// ---------------------------------------------------------------------------
// Kernel 2: 256x256 8-phase GEMM  C[m][n] = sum_k A[m][k]*Wt[n][k] + bias[n]
// (round-2 proven: 44.4 us, 0 bank conflicts). 8 waves (2M x 4N), BK=64,
// double-buffered 128 KiB LDS, counted vmcnt, XOR-swizzled LDS
// (inverse-swizzled global source + swizzled ds_read).
// ---------------------------------------------------------------------------
#define BM 256
#define BN 256
#define BK 64
#define NT (HID / BK)  // 16 K-tiles

__global__ __launch_bounds__(512, 2) void gemm_k(const bf16* __restrict__ A,
                                                 const bf16* __restrict__ Bt,
                                                 const float* __restrict__ bias,
                                                 float* __restrict__ C) {
    // LDS: [buf(2)][mat(2): A,B][row 256][64 bf16] = 131072 B
    __shared__ __attribute__((aligned(16))) char lds[131072];

    const int tid = threadIdx.x;
    const int w = tid >> 6, ln = tid & 63;
    const int wm = w >> 2, wn = w & 3;
    const int fr = ln & 15, fq = ln >> 4;

    // XCD-chunked bijective swizzle (grid=256, 256%8==0)
    int orig = blockIdx.x;
    int wg = (orig & 7) * 32 + (orig >> 3);
    int bm = wg >> 2, bn = wg & 3;  // 64 x 4 tiles

    const bf16* Ab = A + (size_t)bm * BM * HID;
    const bf16* Bb = Bt + (size_t)bn * BN * HID;

    // stage one half-tile (128 rows x 64 cols) of mat {0=A,1=B}, rows [R0,R0+128),
    // K-tile kt, into buffer buf.  LDS dest linear; source pre-swizzled so that
    // physical LDS ends up XOR-swizzled: phys = linear ^ ((row&7)<<4).
    auto stage = [&](int buf, int mat, int R0, int kt) {
        const char* gsrc = (const char*)(mat ? Bb : Ab);
        char* base = lds + (((buf << 1) | mat) << 15) + (R0 << 7);
        const int kb = kt << 7;  // kt * 64 cols * 2B
#pragma unroll
        for (int l = 0; l < 2; ++l) {
            int c = (l << 9) + tid;              // chunk 0..1023 (16B each)
            int lr = c >> 3;                     // local row 0..127
            int colB = ((c & 7) ^ (lr & 7)) << 4;  // inverse-swizzled source col
            const char* g = gsrc + (size_t)(R0 + lr) * (HID * 2) + kb + colB;
            __builtin_amdgcn_global_load_lds(
                (const __attribute__((address_space(1))) void*)g,
                (__attribute__((address_space(3))) void*)(base + (((l << 9) + (w << 6)) << 4)),
                16, 0, 0);
        }
    };

    // swizzled fragment reads. A-frag i: rows (i*2+wm)*16+fr; B-frag j: rows (j*4+wn)*16+fr
    auto readA = [&](int buf, int i, int ks) -> bf16x8 {
        int r = ((i * 2 + wm) << 4) + fr;
        int off = (r << 7) + (ks << 6) + (fq << 4);
        off ^= (fr & 7) << 4;
        return *(const bf16x8*)(lds + ((buf << 1) << 15) + off);
    };
    auto readB = [&](int buf, int j, int ks) -> bf16x8 {
        int r = ((j * 4 + wn) << 4) + fr;
        int off = (r << 7) + (ks << 6) + (fq << 4);
        off ^= (fr & 7) << 4;
        return *(const bf16x8*)(lds + (((buf << 1) | 1) << 15) + off);
    };

    f32x4 acc[8][4];
#pragma unroll
    for (int i = 0; i < 8; ++i)
#pragma unroll
        for (int j = 0; j < 4; ++j) acc[i][j] = (f32x4){0.f, 0.f, 0.f, 0.f};

    // Prologue: issue order must match steady-state stream:
    // Blo(0), Ahi(0), Alo(0), Bhi(0), Blo(1), Ahi(1)  -> wait all of tile 0 (4 left)
    stage(0, 1, 0, 0);
    stage(0, 0, 128, 0);
    stage(0, 0, 0, 0);
    stage(0, 1, 128, 0);
    stage(1, 1, 0, 1);
    stage(1, 0, 128, 1);
    asm volatile("s_waitcnt vmcnt(4)" ::: "memory");
    __builtin_amdgcn_s_barrier();

    bf16x8 a[8][2], b[4][2];

#pragma unroll 1
    for (int t = 0; t < NT; ++t) {
        const int cur = t & 1, nxt = cur ^ 1;

        // ---- P0: ds_read Alo frags + Blo frags; stage Alo(t+1); MFMA m0-3 x n0-1
#pragma unroll
        for (int i = 0; i < 4; ++i) { a[i][0] = readA(cur, i, 0); a[i][1] = readA(cur, i, 1); }
#pragma unroll
        for (int j = 0; j < 2; ++j) { b[j][0] = readB(cur, j, 0); b[j][1] = readB(cur, j, 1); }
        if (t + 1 < NT) stage(nxt, 0, 0, t + 1);
        __builtin_amdgcn_s_barrier();
        asm volatile("s_waitcnt lgkmcnt(0)" ::: "memory");
        __builtin_amdgcn_sched_barrier(0);
        __builtin_amdgcn_s_setprio(1);
#pragma unroll
        for (int i = 0; i < 4; ++i)
#pragma unroll
            for (int j = 0; j < 2; ++j) {
                acc[i][j] = MFMA(a[i][0], b[j][0], acc[i][j]);
                acc[i][j] = MFMA(a[i][1], b[j][1], acc[i][j]);
            }
        __builtin_amdgcn_s_setprio(0);
        __builtin_amdgcn_s_barrier();

        // ---- P1: ds_read Ahi frags; stage Bhi(t+1); MFMA m4-7 x n0-1
#pragma unroll
        for (int i = 4; i < 8; ++i) { a[i][0] = readA(cur, i, 0); a[i][1] = readA(cur, i, 1); }
        if (t + 1 < NT) stage(nxt, 1, 128, t + 1);
        __builtin_amdgcn_s_barrier();
        asm volatile("s_waitcnt lgkmcnt(0)" ::: "memory");
        __builtin_amdgcn_sched_barrier(0);
        __builtin_amdgcn_s_setprio(1);
#pragma unroll
        for (int i = 4; i < 8; ++i)
#pragma unroll
            for (int j = 0; j < 2; ++j) {
                acc[i][j] = MFMA(a[i][0], b[j][0], acc[i][j]);
                acc[i][j] = MFMA(a[i][1], b[j][1], acc[i][j]);
            }
        __builtin_amdgcn_s_setprio(0);
        __builtin_amdgcn_s_barrier();

        // ---- P2: ds_read Bhi frags; stage Blo(t+2) (into cur: Blo reads done at P0); MFMA m4-7 x n2-3
#pragma unroll
        for (int j = 2; j < 4; ++j) { b[j][0] = readB(cur, j, 0); b[j][1] = readB(cur, j, 1); }
        if (t + 2 < NT) stage(cur, 1, 0, t + 2);
        __builtin_amdgcn_s_barrier();
        asm volatile("s_waitcnt lgkmcnt(0)" ::: "memory");
        __builtin_amdgcn_sched_barrier(0);
        __builtin_amdgcn_s_setprio(1);
#pragma unroll
        for (int i = 4; i < 8; ++i)
#pragma unroll
            for (int j = 2; j < 4; ++j) {
                acc[i][j] = MFMA(a[i][0], b[j][0], acc[i][j]);
                acc[i][j] = MFMA(a[i][1], b[j][1], acc[i][j]);
            }
        __builtin_amdgcn_s_setprio(0);
        __builtin_amdgcn_s_barrier();

        // ---- P3: stage Ahi(t+2) (Ahi reads done at P1); MFMA m0-3 x n2-3; counted vmcnt
        if (t + 2 < NT) stage(cur, 0, 128, t + 2);
        __builtin_amdgcn_s_barrier();
        __builtin_amdgcn_s_setprio(1);
#pragma unroll
        for (int i = 0; i < 4; ++i)
#pragma unroll
            for (int j = 2; j < 4; ++j) {
                acc[i][j] = MFMA(a[i][0], b[j][0], acc[i][j]);
                acc[i][j] = MFMA(a[i][1], b[j][1], acc[i][j]);
            }
        __builtin_amdgcn_s_setprio(0);
        // wait: all 4 halves of tile t+1 landed; leave tile t+2's (if staged) in flight
        if (t + 2 < NT) {
            asm volatile("s_waitcnt vmcnt(4)" ::: "memory");
        } else if (t + 1 < NT) {
            asm volatile("s_waitcnt vmcnt(0)" ::: "memory");
        }
        __builtin_amdgcn_sched_barrier(0);
        __builtin_amdgcn_s_barrier();
    }

    // Epilogue: C/D layout col = lane&15, row = (lane>>4)*4 + reg
#pragma unroll
    for (int j = 0; j < 4; ++j) {
        int col = bn * BN + ((j * 4 + wn) << 4) + fr;
        float bv = bias[col];
#pragma unroll
        for (int i = 0; i < 8; ++i) {
            int row0 = bm * BM + ((i * 2 + wm) << 4) + (fq << 2);
#pragma unroll
            for (int jj = 0; jj < 4; ++jj)
                C[(size_t)(row0 + jj) * HID + col] = acc[i][j][jj] + bv;
        }
    }
}

// ---------------------------------------------------------------------------
extern "C" void kernel_launch(void* const* d_in, const int* in_sizes, int n_in,
                              void* d_out, int out_size, void* d_ws, size_t ws_size,
                              hipStream_t stream) {
    const float* x   = (const float*)d_in[0];
    const float* lng = (const float*)d_in[1];
    const float* lnb = (const float*)d_in[2];
    const float* W   = (const float*)d_in[3];
    const float* db  = (const float*)d_in[4];
    float* out = (float*)d_out;

    bf16* A  = (bf16*)d_ws;                                     // 32 MB
    bf16* Wt = (bf16*)((char*)d_ws + (size_t)MROWS * HID * 2);  // 2 MB

    wt_k<<<HID / 16, 256, 0, stream>>>(W, Wt);
    prep_k<<<MROWS, 256, 0, stream>>>(x, lng, lnb, A);
    gemm_k<<<(MROWS / BM) * (HID / BN), 512, 0, stream>>>(A, Wt, db, out);
}